// Round 7
// baseline (779.623 us; speedup 1.0000x reference)
//
#include <hip/hip_runtime.h>
#include <math.h>

// Problem constants
#define NB 128
#define NI 2048
#define NU 16
#define NJ 32
#define NV 16
#define NJV 512

#define BI 16
#define IC (NI / BI)   // 128

typedef __attribute__((ext_vector_type(8))) short  short8v;  // bf16 x8 (4 VGPR)
typedef __attribute__((ext_vector_type(4))) float  float4v;

// ---------------- bf16 convert helpers ----------------
__device__ __forceinline__ unsigned int bf16rne(float f) {
    unsigned int u = __float_as_uint(f);
    return (u + 0x7FFFu + ((u >> 16) & 1u)) >> 16;
}
__device__ __forceinline__ unsigned int bfp(float a, float b) {
    return bf16rne(a) | (bf16rne(b) << 16);
}

// Wb16 layout: T = (i*32 + t)*32 + h, 8 bf16 per T (16B).
// h = g1*16 + c holds W[i][j=t][v=c][u = g1*8 .. g1*8+7].
__global__ __launch_bounds__(256)
void convert_W_kernel(const float* __restrict__ W, uint4* __restrict__ Wb) {
    int T = blockIdx.x * 256 + threadIdx.x;          // 2,097,152
    int h = T & 31, t = (T >> 5) & 31, i = T >> 10;
    int c = h & 15, g1 = h >> 4;
    const float* src = W + ((size_t)(i * 512 + t * 16 + c) * 16 + g1 * 8);
    float4 f0 = *(const float4*)src;
    float4 f1 = *(const float4*)(src + 4);
    uint4 o;
    o.x = bfp(f0.x, f0.y); o.y = bfp(f0.z, f0.w);
    o.z = bfp(f1.x, f1.y); o.w = bfp(f1.z, f1.w);
    Wb[T] = o;
}

// xb16 layout: T = (bt*2048 + i)*32 + h; h = g1*16 + c holds
// x[bt*16 + c][i][u = g1*8 .. g1*8+7].
__global__ __launch_bounds__(256)
void convert_x_kernel(const float* __restrict__ x, uint4* __restrict__ xb) {
    int T = blockIdx.x * 256 + threadIdx.x;          // 524,288
    int h = T & 31, i = (T >> 5) & 2047, bt = T >> 16;
    int c = h & 15, g1 = h >> 4;
    const float* src = x + ((size_t)(bt * 16 + c) * 2048 + i) * 16 + g1 * 8;
    float4 f0 = *(const float4*)src;
    float4 f1 = *(const float4*)(src + 4);
    uint4 o;
    o.x = bfp(f0.x, f0.y); o.y = bfp(f0.z, f0.w);
    o.z = bfp(f1.x, f1.y); o.w = bfp(f1.z, f1.w);
    xb[T] = o;
}

// ---------------- MFMA pass kernel ----------------
// 2-wave blocks: wave = j-half jh; bt = blockIdx.y. Grid (128, 8) = 1024 blocks,
// fully resident at 2 waves/SIMD -> 4 independent blocks per CU.
// MFMA 16x16x32 bf16 with k-duplication -> D = 2*u (0.5 folded into exp/inv/scale).
// D layout: col=lane&15=b_local, row=(lane>>4)*4+r = v.
template<int MODE>
__global__ __launch_bounds__(128, 2)
void pass_mfma(const char* __restrict__ Wb, const char* __restrict__ xb,
               const float* __restrict__ Vacc, float* __restrict__ s_out)
{
    __shared__ float xch[2][2][16];
    const int tid  = threadIdx.x;
    const int lane = tid & 63;
    const int wave = tid >> 6;       // = jh
    const int c = lane & 15, g = lane >> 4;
    const int jh = wave;
    const int bt = blockIdx.y;       // 0..7
    const int ibase = blockIdx.x * BI;
    const int hh = (g & 1) * 16 + c;

    const char* Abase = Wb + (size_t)ibase * 16384 + jh * 8192 + hh * 16;   // + il*16384 + t*512
    const char* Bbase = xb + (size_t)bt * 1048576 + (size_t)ibase * 512 + hh * 16;  // + il*512
    const float* vbase = Vacc + ((size_t)(bt * 16 + c) * 512 + jh * 256 + g * 4);   // + t*16

    float4v s_loc[16];
#pragma unroll
    for (int t = 0; t < 16; ++t) s_loc[t] = (float4v)(0.f);

    for (int il = 0; il < BI; ++il) {
        const short8v bfrag = *reinterpret_cast<const short8v*>(Bbase + (size_t)il * 512);
        const char* Ap = Abase + (size_t)il * 16384;

        if (MODE == 0) {
            // pure accumulating GEMM: s (x2) accumulates in the MFMA C operand
#pragma unroll
            for (int t = 0; t < 16; ++t) {
                short8v a = *reinterpret_cast<const short8v*>(Ap + t * 512);
                s_loc[t] = __builtin_amdgcn_mfma_f32_16x16x32_bf16(a, bfrag, s_loc[t], 0, 0, 0);
            }
        } else {
            float4v uv[16];
#pragma unroll
            for (int t = 0; t < 16; ++t) {
                short8v a = *reinterpret_cast<const short8v*>(Ap + t * 512);
                uv[t] = __builtin_amdgcn_mfma_f32_16x16x32_bf16(a, bfrag, (float4v)(0.f), 0, 0, 0);
            }

            // logits: p[t] = sum_v uv*vacc (uv = 2u; true logit = 0.5*p after reduce)
            float p[16];
#pragma unroll
            for (int t = 0; t < 16; ++t) {
                float4 vc = *(const float4*)(vbase + t * 16);
                float a = uv[t][0] * vc.x;
                a = fmaf(uv[t][1], vc.y, a);
                a = fmaf(uv[t][2], vc.z, a);
                a = fmaf(uv[t][3], vc.w, a);
                p[t] = a;
            }
            // reduce over g: xor16 (ds_swizzle) + xor32 (shfl)
#pragma unroll
            for (int t = 0; t < 16; ++t)
                p[t] += __int_as_float(__builtin_amdgcn_ds_swizzle(__float_as_int(p[t]), 0x401F));
#pragma unroll
            for (int t = 0; t < 16; ++t)
                p[t] += __shfl_xor(p[t], 32, 64);

            // exp + half-sum (pairwise tree)
#pragma unroll
            for (int t = 0; t < 16; ++t) p[t] = __expf(p[t] * 0.5f);
            float s01 = ((p[0] + p[1]) + (p[2] + p[3])) + ((p[4] + p[5]) + (p[6] + p[7]));
            float s23 = ((p[8] + p[9]) + (p[10] + p[11])) + ((p[12] + p[13]) + (p[14] + p[15]));
            float sl = s01 + s23;

            // cross-wave exchange of the j-half exp-sums (partner = wave^1)
            const int par = il & 1;
            if (lane < 16) xch[par][wave][lane] = sl;
            asm volatile("s_waitcnt lgkmcnt(0)" ::: "memory");
            __builtin_amdgcn_s_barrier();
            float so = xch[par][wave ^ 1][c];
            float inv = __builtin_amdgcn_rcpf(sl + so) * 0.5f;   // 0.5: uv = 2u

#pragma unroll
            for (int t = 0; t < 16; ++t) {
                float cc = p[t] * inv;
#pragma unroll
                for (int r = 0; r < 4; ++r)
                    s_loc[t][r] = fmaf(cc, uv[t][r], s_loc[t][r]);
            }
        }
    }

    const float scale = (MODE == 0) ? (1.0f / 64.0f) : 1.0f;   // 1/32 softmax * 1/2 dup
#pragma unroll
    for (int t = 0; t < 16; ++t)
#pragma unroll
        for (int r = 0; r < 4; ++r)
            atomicAdd(&s_out[(size_t)(bt * 16 + c) * 512 + (jh * 16 + t) * 16 + g * 4 + r],
                      s_loc[t][r] * scale);
}

// ---------------- squash ----------------
__global__ __launch_bounds__(256)
void squash_kernel(const float* __restrict__ s_in, const float* __restrict__ bias,
                   float* __restrict__ Vacc, float* __restrict__ out, int mode)
{
    int idx = blockIdx.x * 256 + threadIdx.x;    // over NB*NJV = 65536
    float s = s_in[idx] + bias[idx & (NJV - 1)];
    float sq = s * s;
#pragma unroll
    for (int m = 1; m < 16; m <<= 1) sq += __shfl_xor(sq, m, 64);
    float val = s * sq / (1.0f + sq) / sqrtf(sq + 1e-9f);
    if (mode == 0)      Vacc[idx] = val;
    else if (mode == 1) Vacc[idx] += val;
    else                out[idx]  = val;
}

// ================= R5 fallback (proven) =================
#define FBI 16
#define FIC (NI / FBI)
#define GLD16(gp, lp) __builtin_amdgcn_global_load_lds( \
    (const __attribute__((address_space(1))) unsigned int*)(gp), \
    (__attribute__((address_space(3))) unsigned int*)(lp), 16, 0, 0)

template<int CTRL>
__device__ __forceinline__ float dpp_add(float x) {
    int t = __builtin_amdgcn_update_dpp(0, __float_as_int(x), CTRL, 0xf, 0xf, true);
    return x + __int_as_float(t);
}
__device__ __forceinline__ float red16(float x) {
    x = dpp_add<0xB1>(x); x = dpp_add<0x4E>(x);
    x = dpp_add<0x141>(x); x = dpp_add<0x140>(x);
    return x;
}

template<int MODE>
__global__ __launch_bounds__(256, 1)
void pass_fb(const float* __restrict__ x, const float* __restrict__ W,
             const float* __restrict__ Vacc, float* __restrict__ s_out)
{
    __shared__ float Wlds[2][8192];
    const int tid = threadIdx.x, lane = tid & 63, wave = tid >> 6;
    const int ibase = blockIdx.x * FBI;
    const int b0 = blockIdx.y * 32 + wave * 8;
    const int soff = ((tid >> 4) & 3) * 1024 + (tid & 15) * 64 + (tid >> 6) * 16;
    const char* Wbp = (const char*)W;
#define FSTAGE(i_, buf_) { const char* srcp = Wbp + (size_t)(i_) * 32768 + soff; \
    _Pragma("unroll") for (int p = 0; p < 8; ++p) \
        GLD16(srcp + p * 4096, &Wlds[buf_][p * 1024 + tid * 4]); }
    float vacc[8][8];
    if (MODE) {
#pragma unroll
        for (int b = 0; b < 8; ++b)
#pragma unroll
            for (int k = 0; k < 8; ++k)
                vacc[b][k] = Vacc[(size_t)(b0 + b) * NJV + lane + 64 * k];
    }
    float s_local[8][8];
#pragma unroll
    for (int b = 0; b < 8; ++b)
#pragma unroll
        for (int k = 0; k < 8; ++k) s_local[b][k] = 0.f;
    float uv[8][8];
    FSTAGE(ibase, 0);
    for (int il = 0; il < FBI; ++il) {
        const int i = ibase + il, cur = il & 1;
        if (il < FBI - 1) {
            FSTAGE(i + 1, cur ^ 1);
            asm volatile("s_waitcnt vmcnt(8)" ::: "memory");
        } else {
            asm volatile("s_waitcnt vmcnt(0)" ::: "memory");
        }
        __builtin_amdgcn_s_barrier();
        asm volatile("" ::: "memory");
#pragma unroll
        for (int q = 0; q < 4; ++q) {
            float4 xv[8];
#pragma unroll
            for (int b = 0; b < 8; ++b)
                xv[b] = *(const float4*)(x + ((size_t)(b0 + b) * NI + i) * NU + q * 4);
#pragma unroll
            for (int k = 0; k < 8; ++k) {
                float4 w = *(const float4*)&Wlds[cur][(k * 4 + q) * 256 + lane * 4];
#pragma unroll
                for (int b = 0; b < 8; ++b) {
                    if (MODE) {
                        float a = (q == 0) ? xv[b].x * w.x : fmaf(xv[b].x, w.x, uv[b][k]);
                        a = fmaf(xv[b].y, w.y, a); a = fmaf(xv[b].z, w.z, a);
                        a = fmaf(xv[b].w, w.w, a); uv[b][k] = a;
                    } else {
                        float a = fmaf(xv[b].x, w.x, s_local[b][k]);
                        a = fmaf(xv[b].y, w.y, a); a = fmaf(xv[b].z, w.z, a);
                        a = fmaf(xv[b].w, w.w, a); s_local[b][k] = a;
                    }
                }
            }
        }
        if (MODE) {
#pragma unroll
            for (int b = 0; b < 8; ++b) {
                float p8[8];
#pragma unroll
                for (int k = 0; k < 8; ++k) p8[k] = uv[b][k] * vacc[b][k];
#pragma unroll
                for (int k = 0; k < 8; ++k) p8[k] = red16(p8[k]);
                float sl = 0.f;
#pragma unroll
                for (int k = 0; k < 8; ++k) { p8[k] = __expf(p8[k]); sl += p8[k]; }
                sl += __int_as_float(__builtin_amdgcn_ds_swizzle(__float_as_int(sl), 0x401F));
                sl += __int_as_float(__builtin_amdgcn_ds_bpermute((lane ^ 32) << 2,
                                                                  __float_as_int(sl)));
                float inv = __builtin_amdgcn_rcpf(sl);
#pragma unroll
                for (int k = 0; k < 8; ++k)
                    s_local[b][k] = fmaf(p8[k] * inv, uv[b][k], s_local[b][k]);
            }
        }
        asm volatile("" ::: "memory");
        __builtin_amdgcn_s_barrier();
        asm volatile("" ::: "memory");
    }
    const float scale = (MODE == 0) ? (1.0f / NJ) : 1.0f;
#pragma unroll
    for (int b = 0; b < 8; ++b)
#pragma unroll
        for (int k = 0; k < 8; ++k)
            atomicAdd(&s_out[(size_t)(b0 + b) * NJV + lane + 64 * k],
                      s_local[b][k] * scale);
#undef FSTAGE
}

// ================= launch =================
extern "C" void kernel_launch(void* const* d_in, const int* in_sizes, int n_in,
                              void* d_out, int out_size, void* d_ws, size_t ws_size,
                              hipStream_t stream)
{
    const float* x    = (const float*)d_in[0];
    const float* W    = (const float*)d_in[1];
    const float* bias = (const float*)d_in[2];
    float* out = (float*)d_out;

    float* s_buf = (float*)d_ws;             // 256 KB
    float* Vacc  = s_buf + NB * NJV;         // 256 KB
    char*  Wb16  = (char*)(Vacc + NB * NJV); // 33.5 MB
    char*  xb16  = Wb16 + (size_t)16777216 * 2;  // 8.4 MB

    const size_t NEED = 2u * NB * NJV * 4 + 33554432u + 8388608u;

    dim3 sgrid(NB * NJV / 256), sblk(256);
    size_t s_bytes = (size_t)NB * NJV * sizeof(float);

    if (ws_size >= NEED) {
        convert_W_kernel<<<8192, 256, 0, stream>>>(W, (uint4*)Wb16);
        convert_x_kernel<<<2048, 256, 0, stream>>>(x, (uint4*)xb16);

        dim3 grid(IC, 8), blk(128);

        (void)hipMemsetAsync(s_buf, 0, s_bytes, stream);
        pass_mfma<0><<<grid, blk, 0, stream>>>(Wb16, xb16, Vacc, s_buf);
        squash_kernel<<<sgrid, sblk, 0, stream>>>(s_buf, bias, Vacc, out, 0);

        (void)hipMemsetAsync(s_buf, 0, s_bytes, stream);
        pass_mfma<1><<<grid, blk, 0, stream>>>(Wb16, xb16, Vacc, s_buf);
        squash_kernel<<<sgrid, sblk, 0, stream>>>(s_buf, bias, Vacc, out, 1);

        (void)hipMemsetAsync(s_buf, 0, s_bytes, stream);
        pass_mfma<1><<<grid, blk, 0, stream>>>(Wb16, xb16, Vacc, s_buf);
        squash_kernel<<<sgrid, sblk, 0, stream>>>(s_buf, bias, Vacc, out, 2);
    } else {
        dim3 grid(FIC, 4), blk(256);

        (void)hipMemsetAsync(s_buf, 0, s_bytes, stream);
        pass_fb<0><<<grid, blk, 0, stream>>>(x, W, Vacc, s_buf);
        squash_kernel<<<sgrid, sblk, 0, stream>>>(s_buf, bias, Vacc, out, 0);

        (void)hipMemsetAsync(s_buf, 0, s_bytes, stream);
        pass_fb<1><<<grid, blk, 0, stream>>>(x, W, Vacc, s_buf);
        squash_kernel<<<sgrid, sblk, 0, stream>>>(s_buf, bias, Vacc, out, 1);

        (void)hipMemsetAsync(s_buf, 0, s_bytes, stream);
        pass_fb<1><<<grid, blk, 0, stream>>>(x, W, Vacc, s_buf);
        squash_kernel<<<sgrid, sblk, 0, stream>>>(s_buf, bias, Vacc, out, 2);
    }
}

// Round 8
// 751.075 us; speedup vs baseline: 1.0380x; 1.0380x over previous
//
#include <hip/hip_runtime.h>
#include <math.h>

// Problem constants
#define NB 128
#define NI 2048
#define NU 16
#define NJ 32
#define NV 16
#define NJV 512

#define BI 16
#define IC (NI / BI)   // 128

typedef __attribute__((ext_vector_type(8))) short  short8v;  // bf16 x8 (4 VGPR)
typedef __attribute__((ext_vector_type(4))) float  float4v;

#define GLD16(gp, lp) __builtin_amdgcn_global_load_lds( \
    (const __attribute__((address_space(1))) unsigned int*)(gp), \
    (__attribute__((address_space(3))) unsigned int*)(lp), 16, 0, 0)

// ---------------- bf16 convert helpers ----------------
__device__ __forceinline__ unsigned int bf16rne(float f) {
    unsigned int u = __float_as_uint(f);
    return (u + 0x7FFFu + ((u >> 16) & 1u)) >> 16;
}
__device__ __forceinline__ unsigned int bfp(float a, float b) {
    return bf16rne(a) | (bf16rne(b) << 16);
}

// Wb16 layout: T = (i*32 + t)*32 + h, 8 bf16 per T (16B).
// h = g1*16 + c holds W[i][j=t][v=c][u = g1*8 .. g1*8+7].
__global__ __launch_bounds__(256)
void convert_W_kernel(const float* __restrict__ W, uint4* __restrict__ Wb) {
    int T = blockIdx.x * 256 + threadIdx.x;          // 2,097,152
    int h = T & 31, t = (T >> 5) & 31, i = T >> 10;
    int c = h & 15, g1 = h >> 4;
    const float* src = W + ((size_t)(i * 512 + t * 16 + c) * 16 + g1 * 8);
    float4 f0 = *(const float4*)src;
    float4 f1 = *(const float4*)(src + 4);
    uint4 o;
    o.x = bfp(f0.x, f0.y); o.y = bfp(f0.z, f0.w);
    o.z = bfp(f1.x, f1.y); o.w = bfp(f1.z, f1.w);
    Wb[T] = o;
}

// xb16 layout: T = (bt*2048 + i)*32 + h; h = g1*16 + c holds
// x[bt*16 + c][i][u = g1*8 .. g1*8+7].
__global__ __launch_bounds__(256)
void convert_x_kernel(const float* __restrict__ x, uint4* __restrict__ xb) {
    int T = blockIdx.x * 256 + threadIdx.x;          // 524,288
    int h = T & 31, i = (T >> 5) & 2047, bt = T >> 16;
    int c = h & 15, g1 = h >> 4;
    const float* src = x + ((size_t)(bt * 16 + c) * 2048 + i) * 16 + g1 * 8;
    float4 f0 = *(const float4*)src;
    float4 f1 = *(const float4*)(src + 4);
    uint4 o;
    o.x = bfp(f0.x, f0.y); o.y = bfp(f0.z, f0.w);
    o.z = bfp(f1.x, f1.y); o.w = bfp(f1.z, f1.w);
    xb[T] = o;
}

// ---------------- MFMA pass kernel ----------------
// 4-wave blocks: wave w -> bt = blockIdx.y*2 + (w>>1), j-half jh = w&1.
// Grid (128, 4) = 512 blocks, 2 blocks/CU (LDS 66 KB). W[i] (16 KB bf16)
// staged to LDS via global_load_lds double-buffer with counted vmcnt.
// MFMA 16x16x32 bf16 with k-duplication -> D = 2*u (0.5 folded into exp/inv/scale).
// D layout: col=lane&15=b_local, row=(lane>>4)*4+r = v.
// Epilogue: s_loc -> padded LDS transpose (aliases W buffers) -> coalesced atomics.
template<int MODE>
__global__ __launch_bounds__(256, 1)
void pass_mfma(const char* __restrict__ Wb, const char* __restrict__ xb,
               const float* __restrict__ Vacc, float* __restrict__ s_out)
{
    __shared__ float smem[16512];    // [0,8192): W dbuf (2x16KB); [8192,8320): xch
                                     // epilogue: [0,16512) = s_lds [32][516]
    const int tid  = threadIdx.x;
    const int lane = tid & 63;
    const int wave = tid >> 6;
    const int c = lane & 15, g = lane >> 4;
    const int jh = wave & 1;
    const int bt = blockIdx.y * 2 + (wave >> 1);
    const int ibase = blockIdx.x * BI;
    const int hh = (g & 1) * 16 + c;

    const char* Bbase = xb + (size_t)bt * 1048576 + (size_t)ibase * 512 + hh * 16;
    const float* vbase = Vacc + ((size_t)(bt * 16 + c) * 512 + jh * 256 + g * 4);

#define STAGE(i_, buf_)                                                         \
    {                                                                           \
        const char* srcp = Wb + (size_t)(i_) * 16384 + tid * 16;                \
        _Pragma("unroll")                                                       \
        for (int p = 0; p < 4; ++p)                                             \
            GLD16(srcp + p * 4096, &smem[(buf_) * 4096 + p * 1024 + tid * 4]);  \
    }

    float4v s_loc[16];
#pragma unroll
    for (int t = 0; t < 16; ++t) s_loc[t] = (float4v)(0.f);

    // prologue: stage i0 into buf0, load first B-frag
    STAGE(ibase, 0);
    short8v bcur = *reinterpret_cast<const short8v*>(Bbase);

    for (int il = 0; il < BI; ++il) {
        const int cur = il & 1;

        if (il < BI - 1) {
            STAGE(ibase + il + 1, cur ^ 1);
            asm volatile("s_waitcnt vmcnt(4)" ::: "memory");  // cur staged; next in flight
        } else {
            asm volatile("s_waitcnt vmcnt(0)" ::: "memory");
        }
        __builtin_amdgcn_s_barrier();
        asm volatile("" ::: "memory");

        // off-chain loads: next B-frag + vacc (L1/L2-hot), issued before MFMA phase
        short8v bnxt = bcur;
        if (il < BI - 1)
            bnxt = *reinterpret_cast<const short8v*>(Bbase + (size_t)(il + 1) * 512);
        float4 vc[16];
        if (MODE) {
#pragma unroll
            for (int t = 0; t < 16; ++t)
                vc[t] = *(const float4*)(vbase + t * 16);
        }

        if (MODE == 0) {
            // pure accumulating GEMM: s (x2) accumulates in the MFMA C operand
#pragma unroll
            for (int t = 0; t < 16; ++t) {
                short8v a = *reinterpret_cast<const short8v*>(
                    &smem[cur * 4096 + jh * 2048 + t * 128 + hh * 4]);
                s_loc[t] = __builtin_amdgcn_mfma_f32_16x16x32_bf16(a, bcur, s_loc[t], 0, 0, 0);
            }
            asm volatile("s_waitcnt lgkmcnt(0)" ::: "memory");
            __builtin_amdgcn_s_barrier();   // buf reads done before next stage
            asm volatile("" ::: "memory");
        } else {
            float4v uv[16];
#pragma unroll
            for (int t = 0; t < 16; ++t) {
                short8v a = *reinterpret_cast<const short8v*>(
                    &smem[cur * 4096 + jh * 2048 + t * 128 + hh * 4]);
                uv[t] = __builtin_amdgcn_mfma_f32_16x16x32_bf16(a, bcur, (float4v)(0.f), 0, 0, 0);
            }

            // logits: p[t] = sum_v uv*vacc (uv = 2u; true logit = 0.5*p after reduce)
            float p[16];
#pragma unroll
            for (int t = 0; t < 16; ++t) {
                float a = uv[t][0] * vc[t].x;
                a = fmaf(uv[t][1], vc[t].y, a);
                a = fmaf(uv[t][2], vc[t].z, a);
                a = fmaf(uv[t][3], vc[t].w, a);
                p[t] = a;
            }
            // reduce over g: xor16 (ds_swizzle) + xor32 (shfl)
#pragma unroll
            for (int t = 0; t < 16; ++t)
                p[t] += __int_as_float(__builtin_amdgcn_ds_swizzle(__float_as_int(p[t]), 0x401F));
#pragma unroll
            for (int t = 0; t < 16; ++t)
                p[t] += __shfl_xor(p[t], 32, 64);

            // exp + half-sum (pairwise tree)
#pragma unroll
            for (int t = 0; t < 16; ++t) p[t] = __expf(p[t] * 0.5f);
            float s01 = ((p[0] + p[1]) + (p[2] + p[3])) + ((p[4] + p[5]) + (p[6] + p[7]));
            float s23 = ((p[8] + p[9]) + (p[10] + p[11])) + ((p[12] + p[13]) + (p[14] + p[15]));
            float sl = s01 + s23;

            // cross-wave exchange of j-half exp-sums (partner = wave^1, same bt)
            const int par = il & 1;
            if (lane < 16) smem[8192 + par * 64 + wave * 16 + lane] = sl;
            asm volatile("s_waitcnt lgkmcnt(0)" ::: "memory");
            __builtin_amdgcn_s_barrier();   // also: buf reads done before next stage
            asm volatile("" ::: "memory");
            float so = smem[8192 + par * 64 + (wave ^ 1) * 16 + c];
            float inv = __builtin_amdgcn_rcpf(sl + so) * 0.5f;   // 0.5: uv = 2u

#pragma unroll
            for (int t = 0; t < 16; ++t) {
                float cc = p[t] * inv;
#pragma unroll
                for (int r = 0; r < 4; ++r)
                    s_loc[t][r] = fmaf(cc, uv[t][r], s_loc[t][r]);
            }
        }
        bcur = bnxt;
    }

    // ---- epilogue: transpose via LDS (aliases W bufs; loop fully done), then
    // coalesced atomics. s_lds[b_loc][jv] padded to 516 floats/row.
    asm volatile("" ::: "memory");
    __builtin_amdgcn_s_barrier();
    asm volatile("" ::: "memory");

    const float scale = (MODE == 0) ? (1.0f / 64.0f) : 1.0f;   // 1/32 softmax * 1/2 dup
    const int b_loc = (wave >> 1) * 16 + c;
#pragma unroll
    for (int t = 0; t < 16; ++t) {
        float4 o;
        o.x = s_loc[t][0] * scale; o.y = s_loc[t][1] * scale;
        o.z = s_loc[t][2] * scale; o.w = s_loc[t][3] * scale;
        *(float4*)&smem[b_loc * 516 + jh * 256 + t * 16 + g * 4] = o;
    }
    asm volatile("s_waitcnt lgkmcnt(0)" ::: "memory");
    __builtin_amdgcn_s_barrier();
    asm volatile("" ::: "memory");

    float* outb = s_out + (size_t)blockIdx.y * 32 * 512;
#pragma unroll
    for (int q = 0; q < 16; ++q) {
        int f  = q * 1024 + tid * 4;
        int bl = f >> 9, jv = f & 511;
        float4 v = *(const float4*)&smem[bl * 516 + jv];
        atomicAdd(&outb[bl * 512 + jv + 0], v.x);
        atomicAdd(&outb[bl * 512 + jv + 1], v.y);
        atomicAdd(&outb[bl * 512 + jv + 2], v.z);
        atomicAdd(&outb[bl * 512 + jv + 3], v.w);
    }
#undef STAGE
}

// ---------------- squash ----------------
__global__ __launch_bounds__(256)
void squash_kernel(const float* __restrict__ s_in, const float* __restrict__ bias,
                   float* __restrict__ Vacc, float* __restrict__ out, int mode)
{
    int idx = blockIdx.x * 256 + threadIdx.x;    // over NB*NJV = 65536
    float s = s_in[idx] + bias[idx & (NJV - 1)];
    float sq = s * s;
#pragma unroll
    for (int m = 1; m < 16; m <<= 1) sq += __shfl_xor(sq, m, 64);
    float val = s * sq / (1.0f + sq) / sqrtf(sq + 1e-9f);
    if (mode == 0)      Vacc[idx] = val;
    else if (mode == 1) Vacc[idx] += val;
    else                out[idx]  = val;
}

// ================= R5 fallback (proven) =================
#define FBI 16
#define FIC (NI / FBI)

template<int CTRL>
__device__ __forceinline__ float dpp_add(float x) {
    int t = __builtin_amdgcn_update_dpp(0, __float_as_int(x), CTRL, 0xf, 0xf, true);
    return x + __int_as_float(t);
}
__device__ __forceinline__ float red16(float x) {
    x = dpp_add<0xB1>(x); x = dpp_add<0x4E>(x);
    x = dpp_add<0x141>(x); x = dpp_add<0x140>(x);
    return x;
}

template<int MODE>
__global__ __launch_bounds__(256, 1)
void pass_fb(const float* __restrict__ x, const float* __restrict__ W,
             const float* __restrict__ Vacc, float* __restrict__ s_out)
{
    __shared__ float Wlds[2][8192];
    const int tid = threadIdx.x, lane = tid & 63, wave = tid >> 6;
    const int ibase = blockIdx.x * FBI;
    const int b0 = blockIdx.y * 32 + wave * 8;
    const int soff = ((tid >> 4) & 3) * 1024 + (tid & 15) * 64 + (tid >> 6) * 16;
    const char* Wbp = (const char*)W;
#define FSTAGE(i_, buf_) { const char* srcp = Wbp + (size_t)(i_) * 32768 + soff; \
    _Pragma("unroll") for (int p = 0; p < 8; ++p) \
        GLD16(srcp + p * 4096, &Wlds[buf_][p * 1024 + tid * 4]); }
    float vacc[8][8];
    if (MODE) {
#pragma unroll
        for (int b = 0; b < 8; ++b)
#pragma unroll
            for (int k = 0; k < 8; ++k)
                vacc[b][k] = Vacc[(size_t)(b0 + b) * NJV + lane + 64 * k];
    }
    float s_local[8][8];
#pragma unroll
    for (int b = 0; b < 8; ++b)
#pragma unroll
        for (int k = 0; k < 8; ++k) s_local[b][k] = 0.f;
    float uv[8][8];
    FSTAGE(ibase, 0);
    for (int il = 0; il < FBI; ++il) {
        const int i = ibase + il, cur = il & 1;
        if (il < FBI - 1) {
            FSTAGE(i + 1, cur ^ 1);
            asm volatile("s_waitcnt vmcnt(8)" ::: "memory");
        } else {
            asm volatile("s_waitcnt vmcnt(0)" ::: "memory");
        }
        __builtin_amdgcn_s_barrier();
        asm volatile("" ::: "memory");
#pragma unroll
        for (int q = 0; q < 4; ++q) {
            float4 xv[8];
#pragma unroll
            for (int b = 0; b < 8; ++b)
                xv[b] = *(const float4*)(x + ((size_t)(b0 + b) * NI + i) * NU + q * 4);
#pragma unroll
            for (int k = 0; k < 8; ++k) {
                float4 w = *(const float4*)&Wlds[cur][(k * 4 + q) * 256 + lane * 4];
#pragma unroll
                for (int b = 0; b < 8; ++b) {
                    if (MODE) {
                        float a = (q == 0) ? xv[b].x * w.x : fmaf(xv[b].x, w.x, uv[b][k]);
                        a = fmaf(xv[b].y, w.y, a); a = fmaf(xv[b].z, w.z, a);
                        a = fmaf(xv[b].w, w.w, a); uv[b][k] = a;
                    } else {
                        float a = fmaf(xv[b].x, w.x, s_local[b][k]);
                        a = fmaf(xv[b].y, w.y, a); a = fmaf(xv[b].z, w.z, a);
                        a = fmaf(xv[b].w, w.w, a); s_local[b][k] = a;
                    }
                }
            }
        }
        if (MODE) {
#pragma unroll
            for (int b = 0; b < 8; ++b) {
                float p8[8];
#pragma unroll
                for (int k = 0; k < 8; ++k) p8[k] = uv[b][k] * vacc[b][k];
#pragma unroll
                for (int k = 0; k < 8; ++k) p8[k] = red16(p8[k]);
                float sl = 0.f;
#pragma unroll
                for (int k = 0; k < 8; ++k) { p8[k] = __expf(p8[k]); sl += p8[k]; }
                sl += __int_as_float(__builtin_amdgcn_ds_swizzle(__float_as_int(sl), 0x401F));
                sl += __int_as_float(__builtin_amdgcn_ds_bpermute((lane ^ 32) << 2,
                                                                  __float_as_int(sl)));
                float inv = __builtin_amdgcn_rcpf(sl);
#pragma unroll
                for (int k = 0; k < 8; ++k)
                    s_local[b][k] = fmaf(p8[k] * inv, uv[b][k], s_local[b][k]);
            }
        }
        asm volatile("" ::: "memory");
        __builtin_amdgcn_s_barrier();
        asm volatile("" ::: "memory");
    }
    const float scale = (MODE == 0) ? (1.0f / NJ) : 1.0f;
#pragma unroll
    for (int b = 0; b < 8; ++b)
#pragma unroll
        for (int k = 0; k < 8; ++k)
            atomicAdd(&s_out[(size_t)(b0 + b) * NJV + lane + 64 * k],
                      s_local[b][k] * scale);
#undef FSTAGE
}

// ================= launch =================
extern "C" void kernel_launch(void* const* d_in, const int* in_sizes, int n_in,
                              void* d_out, int out_size, void* d_ws, size_t ws_size,
                              hipStream_t stream)
{
    const float* x    = (const float*)d_in[0];
    const float* W    = (const float*)d_in[1];
    const float* bias = (const float*)d_in[2];
    float* out = (float*)d_out;

    float* s_buf = (float*)d_ws;             // 256 KB
    float* Vacc  = s_buf + NB * NJV;         // 256 KB
    char*  Wb16  = (char*)(Vacc + NB * NJV); // 33.5 MB
    char*  xb16  = Wb16 + (size_t)16777216 * 2;  // 8.4 MB

    const size_t NEED = 2u * NB * NJV * 4 + 33554432u + 8388608u;

    dim3 sgrid(NB * NJV / 256), sblk(256);
    size_t s_bytes = (size_t)NB * NJV * sizeof(float);

    if (ws_size >= NEED) {
        convert_W_kernel<<<8192, 256, 0, stream>>>(W, (uint4*)Wb16);
        convert_x_kernel<<<2048, 256, 0, stream>>>(x, (uint4*)xb16);

        dim3 grid(IC, 4), blk(256);

        (void)hipMemsetAsync(s_buf, 0, s_bytes, stream);
        pass_mfma<0><<<grid, blk, 0, stream>>>(Wb16, xb16, Vacc, s_buf);
        squash_kernel<<<sgrid, sblk, 0, stream>>>(s_buf, bias, Vacc, out, 0);

        (void)hipMemsetAsync(s_buf, 0, s_bytes, stream);
        pass_mfma<1><<<grid, blk, 0, stream>>>(Wb16, xb16, Vacc, s_buf);
        squash_kernel<<<sgrid, sblk, 0, stream>>>(s_buf, bias, Vacc, out, 1);

        (void)hipMemsetAsync(s_buf, 0, s_bytes, stream);
        pass_mfma<1><<<grid, blk, 0, stream>>>(Wb16, xb16, Vacc, s_buf);
        squash_kernel<<<sgrid, sblk, 0, stream>>>(s_buf, bias, Vacc, out, 2);
    } else {
        dim3 grid(FIC, 4), blk(256);

        (void)hipMemsetAsync(s_buf, 0, s_bytes, stream);
        pass_fb<0><<<grid, blk, 0, stream>>>(x, W, Vacc, s_buf);
        squash_kernel<<<sgrid, sblk, 0, stream>>>(s_buf, bias, Vacc, out, 0);

        (void)hipMemsetAsync(s_buf, 0, s_bytes, stream);
        pass_fb<1><<<grid, blk, 0, stream>>>(x, W, Vacc, s_buf);
        squash_kernel<<<sgrid, sblk, 0, stream>>>(s_buf, bias, Vacc, out, 1);

        (void)hipMemsetAsync(s_buf, 0, s_bytes, stream);
        pass_fb<1><<<grid, blk, 0, stream>>>(x, W, Vacc, s_buf);
        squash_kernel<<<sgrid, sblk, 0, stream>>>(s_buf, bias, Vacc, out, 2);
    }
}

// Round 9
// 281.808 us; speedup vs baseline: 2.7665x; 2.6652x over previous
//
#include <hip/hip_runtime.h>
#include <math.h>

// Problem constants
#define NB 128
#define NI 2048
#define NU 16
#define NJ 32
#define NV 16
#define NJV 512

#define BI 16
#define IC (NI / BI)   // 128

typedef __attribute__((ext_vector_type(8))) short  short8v;  // bf16 x8 (4 VGPR)
typedef __attribute__((ext_vector_type(4))) float  float4v;

#define GLD16(gp, lp) __builtin_amdgcn_global_load_lds( \
    (const __attribute__((address_space(1))) unsigned int*)(gp), \
    (__attribute__((address_space(3))) unsigned int*)(lp), 16, 0, 0)

// ---------------- bf16 convert helpers ----------------
__device__ __forceinline__ unsigned int bf16rne(float f) {
    unsigned int u = __float_as_uint(f);
    return (u + 0x7FFFu + ((u >> 16) & 1u)) >> 16;
}
__device__ __forceinline__ unsigned int bfp(float a, float b) {
    return bf16rne(a) | (bf16rne(b) << 16);
}

// Wb16 layout: T = (i*32 + t)*32 + h, 8 bf16 per T (16B).
// h = g1*16 + c holds W[i][j=t][v=c][u = g1*8 .. g1*8+7].
__global__ __launch_bounds__(256)
void convert_W_kernel(const float* __restrict__ W, uint4* __restrict__ Wb) {
    int T = blockIdx.x * 256 + threadIdx.x;          // 2,097,152
    int h = T & 31, t = (T >> 5) & 31, i = T >> 10;
    int c = h & 15, g1 = h >> 4;
    const float* src = W + ((size_t)(i * 512 + t * 16 + c) * 16 + g1 * 8);
    float4 f0 = *(const float4*)src;
    float4 f1 = *(const float4*)(src + 4);
    uint4 o;
    o.x = bfp(f0.x, f0.y); o.y = bfp(f0.z, f0.w);
    o.z = bfp(f1.x, f1.y); o.w = bfp(f1.z, f1.w);
    Wb[T] = o;
}

// xb16 layout: T = (bt*2048 + i)*32 + h; h = g1*16 + c holds
// x[bt*16 + c][i][u = g1*8 .. g1*8+7].
__global__ __launch_bounds__(256)
void convert_x_kernel(const float* __restrict__ x, uint4* __restrict__ xb) {
    int T = blockIdx.x * 256 + threadIdx.x;          // 524,288
    int h = T & 31, i = (T >> 5) & 2047, bt = T >> 16;
    int c = h & 15, g1 = h >> 4;
    const float* src = x + ((size_t)(bt * 16 + c) * 2048 + i) * 16 + g1 * 8;
    float4 f0 = *(const float4*)src;
    float4 f1 = *(const float4*)(src + 4);
    uint4 o;
    o.x = bfp(f0.x, f0.y); o.y = bfp(f0.z, f0.w);
    o.z = bfp(f1.x, f1.y); o.w = bfp(f1.z, f1.w);
    xb[T] = o;
}

// ---------------- MFMA pass kernel (split-K partial output) ----------------
// 4-wave blocks: wave w -> bt = blockIdx.y*2 + (w>>1), j-half jh = w&1.
// Grid (128, 4). LDS 33 KB -> 4 blocks/CU. W[i] staged via global_load_lds
// double-buffer, counted vmcnt. MFMA 16x16x32 bf16, k-duplicated -> D = 2u.
// D layout: col=lane&15=b_local, row=(lane>>4)*4+r = v.
// Output: NO atomics. Block (ic, by) plain-stores its 32x512 partial to
// part[(by*128+ic)*16384 + sf*4], sf=(wave*16+t)*64+lane (coalesced float4).
template<int MODE>
__global__ __launch_bounds__(256, 1)
void pass_mfma(const char* __restrict__ Wb, const char* __restrict__ xb,
               const float* __restrict__ Vacc, float* __restrict__ part)
{
    __shared__ float smem[8320];     // [0,8192): W dbuf (2x16KB); [8192,8320): xch
    const int tid  = threadIdx.x;
    const int lane = tid & 63;
    const int wave = tid >> 6;
    const int c = lane & 15, g = lane >> 4;
    const int jh = wave & 1;
    const int bt = blockIdx.y * 2 + (wave >> 1);
    const int ibase = blockIdx.x * BI;
    const int hh = (g & 1) * 16 + c;

    const char* Bbase = xb + (size_t)bt * 1048576 + (size_t)ibase * 512 + hh * 16;

#define STAGE(i_, buf_)                                                         \
    {                                                                           \
        const char* srcp = Wb + (size_t)(i_) * 16384 + tid * 16;                \
        _Pragma("unroll")                                                       \
        for (int p = 0; p < 4; ++p)                                             \
            GLD16(srcp + p * 4096, &smem[(buf_) * 4096 + p * 1024 + tid * 4]);  \
    }

    // prologue: stage i0 into buf0; load vacc fragments + first B-frag
    STAGE(ibase, 0);
    float4v vc[16];
    if (MODE) {
        const float* vbase = Vacc + ((size_t)(bt * 16 + c) * 512 + jh * 256 + g * 4);
#pragma unroll
        for (int t = 0; t < 16; ++t)
            vc[t] = *reinterpret_cast<const float4v*>(vbase + t * 16);
    }
    short8v bcur = *reinterpret_cast<const short8v*>(Bbase);

    float4v s_loc[16];
#pragma unroll
    for (int t = 0; t < 16; ++t) s_loc[t] = (float4v)(0.f);

    for (int il = 0; il < BI; ++il) {
        const int cur = il & 1;

        if (il < BI - 1) {
            STAGE(ibase + il + 1, cur ^ 1);
            asm volatile("s_waitcnt vmcnt(4)" ::: "memory");  // cur staged; next in flight
        } else {
            asm volatile("s_waitcnt vmcnt(0)" ::: "memory");
        }
        __builtin_amdgcn_s_barrier();
        asm volatile("" ::: "memory");

        // off-chain: next B-frag (L2-hot), issued before MFMA phase
        short8v bnxt = bcur;
        if (il < BI - 1)
            bnxt = *reinterpret_cast<const short8v*>(Bbase + (size_t)(il + 1) * 512);

        if (MODE == 0) {
            // pure accumulating GEMM: s (x2) accumulates in the MFMA C operand
#pragma unroll
            for (int t = 0; t < 16; ++t) {
                short8v a = *reinterpret_cast<const short8v*>(
                    &smem[cur * 4096 + jh * 2048 + t * 128 + hh * 4]);
                s_loc[t] = __builtin_amdgcn_mfma_f32_16x16x32_bf16(a, bcur, s_loc[t], 0, 0, 0);
            }
            asm volatile("s_waitcnt lgkmcnt(0)" ::: "memory");
            __builtin_amdgcn_s_barrier();   // buf reads done before next stage
            asm volatile("" ::: "memory");
        } else {
            float4v uv[16];
#pragma unroll
            for (int t = 0; t < 16; ++t) {
                short8v a = *reinterpret_cast<const short8v*>(
                    &smem[cur * 4096 + jh * 2048 + t * 128 + hh * 4]);
                uv[t] = __builtin_amdgcn_mfma_f32_16x16x32_bf16(a, bcur, (float4v)(0.f), 0, 0, 0);
            }

            // logits: p[t] = sum_v uv*vacc (uv = 2u; true logit = 0.5*p after reduce)
            float p[16];
#pragma unroll
            for (int t = 0; t < 16; ++t) {
                float a = uv[t][0] * vc[t][0];
                a = fmaf(uv[t][1], vc[t][1], a);
                a = fmaf(uv[t][2], vc[t][2], a);
                a = fmaf(uv[t][3], vc[t][3], a);
                p[t] = a;
            }
            // reduce over g: xor16 (ds_swizzle) + xor32 (shfl)
#pragma unroll
            for (int t = 0; t < 16; ++t)
                p[t] += __int_as_float(__builtin_amdgcn_ds_swizzle(__float_as_int(p[t]), 0x401F));
#pragma unroll
            for (int t = 0; t < 16; ++t)
                p[t] += __shfl_xor(p[t], 32, 64);

            // exp + half-sum (pairwise tree)
#pragma unroll
            for (int t = 0; t < 16; ++t) p[t] = __expf(p[t] * 0.5f);
            float s01 = ((p[0] + p[1]) + (p[2] + p[3])) + ((p[4] + p[5]) + (p[6] + p[7]));
            float s23 = ((p[8] + p[9]) + (p[10] + p[11])) + ((p[12] + p[13]) + (p[14] + p[15]));
            float sl = s01 + s23;

            // cross-wave exchange of j-half exp-sums (partner = wave^1, same bt)
            const int par = il & 1;
            if (lane < 16) smem[8192 + par * 64 + wave * 16 + lane] = sl;
            asm volatile("s_waitcnt lgkmcnt(0)" ::: "memory");
            __builtin_amdgcn_s_barrier();   // also: buf reads done before next stage
            asm volatile("" ::: "memory");
            float so = smem[8192 + par * 64 + (wave ^ 1) * 16 + c];
            float inv = __builtin_amdgcn_rcpf(sl + so) * 0.5f;   // 0.5: uv = 2u

#pragma unroll
            for (int t = 0; t < 16; ++t) {
                float cc = p[t] * inv;
#pragma unroll
                for (int r = 0; r < 4; ++r)
                    s_loc[t][r] = fmaf(cc, uv[t][r], s_loc[t][r]);
            }
        }
        bcur = bnxt;
    }

    // epilogue: coalesced plain stores of the block's partial (no atomics)
    const float scale = (MODE == 0) ? (1.0f / 64.0f) : 1.0f;   // 1/32 softmax * 1/2 dup
    float* pb = part + ((size_t)(blockIdx.y * IC + blockIdx.x)) * 16384;
#pragma unroll
    for (int t = 0; t < 16; ++t) {
        float4v o = s_loc[t] * scale;
        *reinterpret_cast<float4v*>(&pb[((wave * 16 + t) * 64 + lane) * 4]) = o;
    }
#undef STAGE
}

// ---------------- fused reduce + bias + squash ----------------
// Slot sfq in [0,16384) float4 units: by = sfq>>12, sf = sfq&4095;
// wave = sf>>10, t = (sf>>6)&15, lane = sf&63 (= tid, blocks of 64), c = lane&15,
// g = lane>>4. Value (r=0..3) is s[b][jv]: b = by*32 + (wave>>1)*16 + c,
// j = (wave&1)*16 + t, v = g*4 + r. The 4 g-groups of a (b,j) sit in one wave
// -> xor16+xor32 gives sum over v. mode 0: Vacc=v; 1: Vacc+=v; 2: out=v.
__global__ __launch_bounds__(64)
void reduce_squash(const float* __restrict__ part, const float* __restrict__ bias,
                   float* __restrict__ Vacc, float* __restrict__ out, int mode)
{
    const int tid = threadIdx.x;
    const int sfq = blockIdx.x * 64 + tid;
    const int by = sfq >> 12, sf = sfq & 4095;
    const int wave = sf >> 10, t = (sf >> 6) & 15;
    const int c = tid & 15, g = (tid >> 4) & 3;

    const float* src = part + (size_t)by * (IC * 16384) + (size_t)sf * 4;
    float4v a0 = (float4v)(0.f), a1 = (float4v)(0.f), a2 = (float4v)(0.f), a3 = (float4v)(0.f);
    for (int ic = 0; ic < IC; ic += 4) {
        a0 += *reinterpret_cast<const float4v*>(src + (size_t)(ic + 0) * 16384);
        a1 += *reinterpret_cast<const float4v*>(src + (size_t)(ic + 1) * 16384);
        a2 += *reinterpret_cast<const float4v*>(src + (size_t)(ic + 2) * 16384);
        a3 += *reinterpret_cast<const float4v*>(src + (size_t)(ic + 3) * 16384);
    }
    float4v s = (a0 + a1) + (a2 + a3);

    const int b = by * 32 + (wave >> 1) * 16 + c;
    const int j = (wave & 1) * 16 + t;
    const float4v bi = *reinterpret_cast<const float4v*>(bias + j * 16 + g * 4);
    s += bi;

    float sq = s[0]*s[0] + s[1]*s[1] + s[2]*s[2] + s[3]*s[3];
    sq += __int_as_float(__builtin_amdgcn_ds_swizzle(__float_as_int(sq), 0x401F));
    sq += __shfl_xor(sq, 32, 64);

    float m = sq / (1.0f + sq) * __builtin_amdgcn_rsqf(sq + 1e-9f);
    float4v val = s * m;

    float* dst = (mode == 2) ? out : Vacc;
    float4v* dp = reinterpret_cast<float4v*>(dst + (size_t)b * 512 + j * 16 + g * 4);
    if (mode == 1) {
        float4v old = *reinterpret_cast<const float4v*>(
            Vacc + (size_t)b * 512 + j * 16 + g * 4);
        *dp = old + val;
    } else {
        *dp = val;
    }
}

// ---------------- squash (fallback path only) ----------------
__global__ __launch_bounds__(256)
void squash_kernel(const float* __restrict__ s_in, const float* __restrict__ bias,
                   float* __restrict__ Vacc, float* __restrict__ out, int mode)
{
    int idx = blockIdx.x * 256 + threadIdx.x;    // over NB*NJV = 65536
    float s = s_in[idx] + bias[idx & (NJV - 1)];
    float sq = s * s;
#pragma unroll
    for (int m = 1; m < 16; m <<= 1) sq += __shfl_xor(sq, m, 64);
    float val = s * sq / (1.0f + sq) / sqrtf(sq + 1e-9f);
    if (mode == 0)      Vacc[idx] = val;
    else if (mode == 1) Vacc[idx] += val;
    else                out[idx]  = val;
}

// ================= R5 fallback (proven) =================
#define FBI 16
#define FIC (NI / FBI)

template<int CTRL>
__device__ __forceinline__ float dpp_add(float x) {
    int t = __builtin_amdgcn_update_dpp(0, __float_as_int(x), CTRL, 0xf, 0xf, true);
    return x + __int_as_float(t);
}
__device__ __forceinline__ float red16(float x) {
    x = dpp_add<0xB1>(x); x = dpp_add<0x4E>(x);
    x = dpp_add<0x141>(x); x = dpp_add<0x140>(x);
    return x;
}

template<int MODE>
__global__ __launch_bounds__(256, 1)
void pass_fb(const float* __restrict__ x, const float* __restrict__ W,
             const float* __restrict__ Vacc, float* __restrict__ s_out)
{
    __shared__ float Wlds[2][8192];
    const int tid = threadIdx.x, lane = tid & 63, wave = tid >> 6;
    const int ibase = blockIdx.x * FBI;
    const int b0 = blockIdx.y * 32 + wave * 8;
    const int soff = ((tid >> 4) & 3) * 1024 + (tid & 15) * 64 + (tid >> 6) * 16;
    const char* Wbp = (const char*)W;
#define FSTAGE(i_, buf_) { const char* srcp = Wbp + (size_t)(i_) * 32768 + soff; \
    _Pragma("unroll") for (int p = 0; p < 8; ++p) \
        GLD16(srcp + p * 4096, &Wlds[buf_][p * 1024 + tid * 4]); }
    float vacc[8][8];
    if (MODE) {
#pragma unroll
        for (int b = 0; b < 8; ++b)
#pragma unroll
            for (int k = 0; k < 8; ++k)
                vacc[b][k] = Vacc[(size_t)(b0 + b) * NJV + lane + 64 * k];
    }
    float s_local[8][8];
#pragma unroll
    for (int b = 0; b < 8; ++b)
#pragma unroll
        for (int k = 0; k < 8; ++k) s_local[b][k] = 0.f;
    float uv[8][8];
    FSTAGE(ibase, 0);
    for (int il = 0; il < FBI; ++il) {
        const int i = ibase + il, cur = il & 1;
        if (il < FBI - 1) {
            FSTAGE(i + 1, cur ^ 1);
            asm volatile("s_waitcnt vmcnt(8)" ::: "memory");
        } else {
            asm volatile("s_waitcnt vmcnt(0)" ::: "memory");
        }
        __builtin_amdgcn_s_barrier();
        asm volatile("" ::: "memory");
#pragma unroll
        for (int q = 0; q < 4; ++q) {
            float4 xv[8];
#pragma unroll
            for (int b = 0; b < 8; ++b)
                xv[b] = *(const float4*)(x + ((size_t)(b0 + b) * NI + i) * NU + q * 4);
#pragma unroll
            for (int k = 0; k < 8; ++k) {
                float4 w = *(const float4*)&Wlds[cur][(k * 4 + q) * 256 + lane * 4];
#pragma unroll
                for (int b = 0; b < 8; ++b) {
                    if (MODE) {
                        float a = (q == 0) ? xv[b].x * w.x : fmaf(xv[b].x, w.x, uv[b][k]);
                        a = fmaf(xv[b].y, w.y, a); a = fmaf(xv[b].z, w.z, a);
                        a = fmaf(xv[b].w, w.w, a); uv[b][k] = a;
                    } else {
                        float a = fmaf(xv[b].x, w.x, s_local[b][k]);
                        a = fmaf(xv[b].y, w.y, a); a = fmaf(xv[b].z, w.z, a);
                        a = fmaf(xv[b].w, w.w, a); s_local[b][k] = a;
                    }
                }
            }
        }
        if (MODE) {
#pragma unroll
            for (int b = 0; b < 8; ++b) {
                float p8[8];
#pragma unroll
                for (int k = 0; k < 8; ++k) p8[k] = uv[b][k] * vacc[b][k];
#pragma unroll
                for (int k = 0; k < 8; ++k) p8[k] = red16(p8[k]);
                float sl = 0.f;
#pragma unroll
                for (int k = 0; k < 8; ++k) { p8[k] = __expf(p8[k]); sl += p8[k]; }
                sl += __int_as_float(__builtin_amdgcn_ds_swizzle(__float_as_int(sl), 0x401F));
                sl += __int_as_float(__builtin_amdgcn_ds_bpermute((lane ^ 32) << 2,
                                                                  __float_as_int(sl)));
                float inv = __builtin_amdgcn_rcpf(sl);
#pragma unroll
                for (int k = 0; k < 8; ++k)
                    s_local[b][k] = fmaf(p8[k] * inv, uv[b][k], s_local[b][k]);
            }
        }
        asm volatile("" ::: "memory");
        __builtin_amdgcn_s_barrier();
        asm volatile("" ::: "memory");
    }
    const float scale = (MODE == 0) ? (1.0f / NJ) : 1.0f;
#pragma unroll
    for (int b = 0; b < 8; ++b)
#pragma unroll
        for (int k = 0; k < 8; ++k)
            atomicAdd(&s_out[(size_t)(b0 + b) * NJV + lane + 64 * k],
                      s_local[b][k] * scale);
#undef FSTAGE
}

// ================= launch =================
extern "C" void kernel_launch(void* const* d_in, const int* in_sizes, int n_in,
                              void* d_out, int out_size, void* d_ws, size_t ws_size,
                              hipStream_t stream)
{
    const float* x    = (const float*)d_in[0];
    const float* W    = (const float*)d_in[1];
    const float* bias = (const float*)d_in[2];
    float* out = (float*)d_out;

    float* s_buf = (float*)d_ws;             // 256 KB (fallback only)
    float* Vacc  = s_buf + NB * NJV;         // 256 KB
    char*  Wb16  = (char*)(Vacc + NB * NJV); // 32 MB
    char*  xb16  = Wb16 + (size_t)33554432;  // 8 MB
    float* part  = (float*)(xb16 + (size_t)8388608);  // 32 MB

    const size_t NEED = 2u * NB * NJV * 4 + 33554432u + 8388608u + 33554432u;

    dim3 sgrid(NB * NJV / 256), sblk(256);
    size_t s_bytes = (size_t)NB * NJV * sizeof(float);

    if (ws_size >= NEED) {
        convert_W_kernel<<<8192, 256, 0, stream>>>(W, (uint4*)Wb16);
        convert_x_kernel<<<2048, 256, 0, stream>>>(x, (uint4*)xb16);

        dim3 grid(IC, 4), blk(256);
        dim3 rgrid(256), rblk(64);

        pass_mfma<0><<<grid, blk, 0, stream>>>(Wb16, xb16, Vacc, part);
        reduce_squash<<<rgrid, rblk, 0, stream>>>(part, bias, Vacc, out, 0);

        pass_mfma<1><<<grid, blk, 0, stream>>>(Wb16, xb16, Vacc, part);
        reduce_squash<<<rgrid, rblk, 0, stream>>>(part, bias, Vacc, out, 1);

        pass_mfma<1><<<grid, blk, 0, stream>>>(Wb16, xb16, Vacc, part);
        reduce_squash<<<rgrid, rblk, 0, stream>>>(part, bias, Vacc, out, 2);
    } else {
        dim3 grid(FIC, 4), blk(256);

        (void)hipMemsetAsync(s_buf, 0, s_bytes, stream);
        pass_fb<0><<<grid, blk, 0, stream>>>(x, W, Vacc, s_buf);
        squash_kernel<<<sgrid, sblk, 0, stream>>>(s_buf, bias, Vacc, out, 0);

        (void)hipMemsetAsync(s_buf, 0, s_bytes, stream);
        pass_fb<1><<<grid, blk, 0, stream>>>(x, W, Vacc, s_buf);
        squash_kernel<<<sgrid, sblk, 0, stream>>>(s_buf, bias, Vacc, out, 1);

        (void)hipMemsetAsync(s_buf, 0, s_bytes, stream);
        pass_fb<1><<<grid, blk, 0, stream>>>(x, W, Vacc, s_buf);
        squash_kernel<<<sgrid, sblk, 0, stream>>>(s_buf, bias, Vacc, out, 2);
    }
}

// Round 10
// 237.317 us; speedup vs baseline: 3.2852x; 1.1875x over previous
//
#include <hip/hip_runtime.h>
#include <math.h>

// Problem constants
#define NB 128
#define NI 2048
#define NU 16
#define NJ 32
#define NV 16
#define NJV 512

#define BI 16
#define IC (NI / BI)   // 128

typedef __attribute__((ext_vector_type(8))) short  short8v;  // bf16 x8 (4 VGPR)
typedef __attribute__((ext_vector_type(4))) float  float4v;

#define GLD16(gp, lp) __builtin_amdgcn_global_load_lds( \
    (const __attribute__((address_space(1))) unsigned int*)(gp), \
    (__attribute__((address_space(3))) unsigned int*)(lp), 16, 0, 0)

// ---------------- bf16 convert helpers ----------------
__device__ __forceinline__ unsigned int bf16rne(float f) {
    unsigned int u = __float_as_uint(f);
    return (u + 0x7FFFu + ((u >> 16) & 1u)) >> 16;
}
__device__ __forceinline__ unsigned int bfp(float a, float b) {
    return bf16rne(a) | (bf16rne(b) << 16);
}

// Wb16 layout: T = (i*32 + j)*32 + h, 8 bf16 per T (16B).
// h = g1*16 + c holds W[i][j][v=c][u = g1*8 .. g1*8+7].
__global__ __launch_bounds__(256)
void convert_W_kernel(const float* __restrict__ W, uint4* __restrict__ Wb) {
    int T = blockIdx.x * 256 + threadIdx.x;          // 2,097,152
    int h = T & 31, t = (T >> 5) & 31, i = T >> 10;
    int c = h & 15, g1 = h >> 4;
    const float* src = W + ((size_t)(i * 512 + t * 16 + c) * 16 + g1 * 8);
    float4 f0 = *(const float4*)src;
    float4 f1 = *(const float4*)(src + 4);
    uint4 o;
    o.x = bfp(f0.x, f0.y); o.y = bfp(f0.z, f0.w);
    o.z = bfp(f1.x, f1.y); o.w = bfp(f1.z, f1.w);
    Wb[T] = o;
}

// xb16 layout: T = (bt*2048 + i)*32 + h; h = g1*16 + c holds
// x[bt*16 + c][i][u = g1*8 .. g1*8+7].
__global__ __launch_bounds__(256)
void convert_x_kernel(const float* __restrict__ x, uint4* __restrict__ xb) {
    int T = blockIdx.x * 256 + threadIdx.x;          // 524,288
    int h = T & 31, i = (T >> 5) & 2047, bt = T >> 16;
    int c = h & 15, g1 = h >> 4;
    const float* src = x + ((size_t)(bt * 16 + c) * 2048 + i) * 16 + g1 * 8;
    float4 f0 = *(const float4*)src;
    float4 f1 = *(const float4*)(src + 4);
    uint4 o;
    o.x = bfp(f0.x, f0.y); o.y = bfp(f0.z, f0.w);
    o.z = bfp(f1.x, f1.y); o.w = bfp(f1.z, f1.w);
    xb[T] = o;
}

// ---------------- MFMA pass kernel (j-quarter waves, split-K output) ----------
// Block = 256 thr = 4 waves; wave = j-quarter jq (j = jq*8 + t, t=0..7).
// bt = blockIdx.y (0..7), i-chunk = blockIdx.x. Grid (128, 8) = 1024 blocks,
// ALL resident: LDS 33 KB -> 4 blocks/CU; VGPR <= 128 -> 4 waves/SIMD.
// W[i] staged via global_load_lds double-buffer, counted vmcnt(4).
// MFMA 16x16x32 bf16, k-duplicated -> D = 2u (0.5 folded into inv).
// D layout: col=lane&15=b_local, row=(lane>>4)*4+r = v.
// Output: plain coalesced stores of the block's 16x512 partial (no atomics).
template<int MODE>
__global__ __launch_bounds__(256, 2)
void pass_mfma(const char* __restrict__ Wb, const char* __restrict__ xb,
               const float* __restrict__ Vacc, float* __restrict__ part)
{
    __shared__ float smem[8320];     // [0,8192): W dbuf (2x16KB); [8192,8320): xch
    const int tid  = threadIdx.x;
    const int lane = tid & 63;
    const int jq   = tid >> 6;       // wave = j-quarter
    const int c = lane & 15, g = lane >> 4;
    const int bt = blockIdx.y;       // 0..7
    const int ibase = blockIdx.x * BI;
    const int hh = (g & 1) * 16 + c;

    const char* Bbase = xb + (size_t)bt * 1048576 + (size_t)ibase * 512 + hh * 16;

#define STAGE(i_, buf_)                                                         \
    {                                                                           \
        const char* srcp = Wb + (size_t)(i_) * 16384 + tid * 16;                \
        _Pragma("unroll")                                                       \
        for (int p = 0; p < 4; ++p)                                             \
            GLD16(srcp + p * 4096, &smem[(buf_) * 4096 + p * 1024 + tid * 4]);  \
    }

    // prologue: stage i0; vacc fragments (8 float4 = 32 VGPR) + first B-frag
    STAGE(ibase, 0);
    float4v vc[8];
    if (MODE) {
        const float* vbase = Vacc + ((size_t)(bt * 16 + c) * 512 + jq * 128 + g * 4);
#pragma unroll
        for (int t = 0; t < 8; ++t)
            vc[t] = *reinterpret_cast<const float4v*>(vbase + t * 16);
    }
    short8v bcur = *reinterpret_cast<const short8v*>(Bbase);

    float4v s_loc[8];
#pragma unroll
    for (int t = 0; t < 8; ++t) s_loc[t] = (float4v)(0.f);

    for (int il = 0; il < BI; ++il) {
        const int cur = il & 1;

        if (il < BI - 1) {
            STAGE(ibase + il + 1, cur ^ 1);
            asm volatile("s_waitcnt vmcnt(4)" ::: "memory");  // cur staged; next in flight
        } else {
            asm volatile("s_waitcnt vmcnt(0)" ::: "memory");
        }
        __builtin_amdgcn_s_barrier();
        asm volatile("" ::: "memory");

        // off-chain: next B-frag (L2-hot)
        short8v bnxt = bcur;
        if (il < BI - 1)
            bnxt = *reinterpret_cast<const short8v*>(Bbase + (size_t)(il + 1) * 512);

        if (MODE == 0) {
            // pure accumulating GEMM: s (x2) accumulates in the MFMA C operand
#pragma unroll
            for (int t = 0; t < 8; ++t) {
                short8v a = *reinterpret_cast<const short8v*>(
                    &smem[cur * 4096 + (jq * 8 + t) * 128 + hh * 4]);
                s_loc[t] = __builtin_amdgcn_mfma_f32_16x16x32_bf16(a, bcur, s_loc[t], 0, 0, 0);
            }
            asm volatile("s_waitcnt lgkmcnt(0)" ::: "memory");
            __builtin_amdgcn_s_barrier();   // buf reads done before next stage
            asm volatile("" ::: "memory");
        } else {
            float4v uv[8];
#pragma unroll
            for (int t = 0; t < 8; ++t) {
                short8v a = *reinterpret_cast<const short8v*>(
                    &smem[cur * 4096 + (jq * 8 + t) * 128 + hh * 4]);
                uv[t] = __builtin_amdgcn_mfma_f32_16x16x32_bf16(a, bcur, (float4v)(0.f), 0, 0, 0);
            }

            // logits: p[t] = sum_v uv*vacc (uv = 2u; 0.5 folded into inv)
            float p[8];
#pragma unroll
            for (int t = 0; t < 8; ++t) {
                float a = uv[t][0] * vc[t][0];
                a = fmaf(uv[t][1], vc[t][1], a);
                a = fmaf(uv[t][2], vc[t][2], a);
                a = fmaf(uv[t][3], vc[t][3], a);
                p[t] = a;
            }
            // reduce over g: xor16 (ds_swizzle) + xor32 (shfl)
#pragma unroll
            for (int t = 0; t < 8; ++t)
                p[t] += __int_as_float(__builtin_amdgcn_ds_swizzle(__float_as_int(p[t]), 0x401F));
#pragma unroll
            for (int t = 0; t < 8; ++t)
                p[t] += __shfl_xor(p[t], 32, 64);

            // exp + quarter-sum (pairwise tree)
#pragma unroll
            for (int t = 0; t < 8; ++t) p[t] = __expf(p[t] * 0.5f);
            float sl = ((p[0] + p[1]) + (p[2] + p[3])) + ((p[4] + p[5]) + (p[6] + p[7]));

            // 4-way cross-wave exchange of quarter exp-sums
            const int par = il & 1;
            if (lane < 16) smem[8192 + par * 64 + jq * 16 + lane] = sl;
            asm volatile("s_waitcnt lgkmcnt(0)" ::: "memory");
            __builtin_amdgcn_s_barrier();   // also: buf reads done before next stage
            asm volatile("" ::: "memory");
            float q0 = smem[8192 + par * 64 + 0 * 16 + c];
            float q1 = smem[8192 + par * 64 + 1 * 16 + c];
            float q2 = smem[8192 + par * 64 + 2 * 16 + c];
            float q3 = smem[8192 + par * 64 + 3 * 16 + c];
            float inv = __builtin_amdgcn_rcpf((q0 + q1) + (q2 + q3)) * 0.5f;  // 0.5: uv=2u

#pragma unroll
            for (int t = 0; t < 8; ++t) {
                float cc = p[t] * inv;
#pragma unroll
                for (int r = 0; r < 4; ++r)
                    s_loc[t][r] = fmaf(cc, uv[t][r], s_loc[t][r]);
            }
        }
        bcur = bnxt;
    }

    // epilogue: coalesced plain stores of the block's 16x512 partial
    const float scale = (MODE == 0) ? (1.0f / 64.0f) : 1.0f;   // 1/32 softmax * 1/2 dup
    float* pb = part + ((size_t)(blockIdx.y * IC + blockIdx.x)) * 8192;
#pragma unroll
    for (int t = 0; t < 8; ++t) {
        float4v o = s_loc[t] * scale;
        *reinterpret_cast<float4v*>(&pb[((jq * 8 + t) * 64 + lane) * 4]) = o;
    }
#undef STAGE
}

// ---------------- fused reduce + bias + squash (4-way ic-split) ----------------
// Slot sfq in [0,16384): bt = sfq>>11, sf = sfq&2047, j = sf>>6, l = sf&63,
// c = l&15, g = l>>4. Value (r) = s[b = bt*16+c][j][v = g*4+r].
// Block = 256 thr: wave w sums ic in [w*32, w*32+32) for slots blockIdx*64 + l.
// Waves 1-3 park partials in LDS; wave 0 combines, adds bias, v-norm via
// xor16+xor32, squashes, stores. mode 0: Vacc=v; 1: Vacc+=v; 2: out=v.
__global__ __launch_bounds__(256)
void reduce_squash(const float* __restrict__ part, const float* __restrict__ bias,
                   float* __restrict__ Vacc, float* __restrict__ out, int mode)
{
    __shared__ float lds[3][64][4];
    const int tid = threadIdx.x;
    const int w = tid >> 6, l = tid & 63;
    const int sfq = blockIdx.x * 64 + l;
    const int bt = sfq >> 11, sf = sfq & 2047;
    const int j = sf >> 6;
    const int c = l & 15, g = (l >> 4) & 3;

    const float* src = part + (size_t)bt * (IC * 8192) + (size_t)sf * 4
                            + (size_t)(w * 32) * 8192;
    float4v a0 = (float4v)(0.f), a1 = (float4v)(0.f),
            a2 = (float4v)(0.f), a3 = (float4v)(0.f);
#pragma unroll
    for (int ic = 0; ic < 32; ic += 4) {
        a0 += *reinterpret_cast<const float4v*>(src + (size_t)(ic + 0) * 8192);
        a1 += *reinterpret_cast<const float4v*>(src + (size_t)(ic + 1) * 8192);
        a2 += *reinterpret_cast<const float4v*>(src + (size_t)(ic + 2) * 8192);
        a3 += *reinterpret_cast<const float4v*>(src + (size_t)(ic + 3) * 8192);
    }
    float4v s = (a0 + a1) + (a2 + a3);

    if (w != 0) {
        lds[w - 1][l][0] = s[0]; lds[w - 1][l][1] = s[1];
        lds[w - 1][l][2] = s[2]; lds[w - 1][l][3] = s[3];
    }
    __syncthreads();
    if (w == 0) {
#pragma unroll
        for (int q = 0; q < 3; ++q) {
            s[0] += lds[q][l][0]; s[1] += lds[q][l][1];
            s[2] += lds[q][l][2]; s[3] += lds[q][l][3];
        }
        const float4v bi = *reinterpret_cast<const float4v*>(bias + j * 16 + g * 4);
        s += bi;

        float sq = s[0]*s[0] + s[1]*s[1] + s[2]*s[2] + s[3]*s[3];
        sq += __int_as_float(__builtin_amdgcn_ds_swizzle(__float_as_int(sq), 0x401F));
        sq += __shfl_xor(sq, 32, 64);

        float m = sq / (1.0f + sq) * __builtin_amdgcn_rsqf(sq + 1e-9f);
        float4v val = s * m;

        const int b = bt * 16 + c;
        float* dst = (mode == 2) ? out : Vacc;
        float4v* dp = reinterpret_cast<float4v*>(dst + (size_t)b * 512 + j * 16 + g * 4);
        if (mode == 1) {
            float4v old = *reinterpret_cast<const float4v*>(
                Vacc + (size_t)b * 512 + j * 16 + g * 4);
            *dp = old + val;
        } else {
            *dp = val;
        }
    }
}

// ---------------- squash (fallback path only) ----------------
__global__ __launch_bounds__(256)
void squash_kernel(const float* __restrict__ s_in, const float* __restrict__ bias,
                   float* __restrict__ Vacc, float* __restrict__ out, int mode)
{
    int idx = blockIdx.x * 256 + threadIdx.x;    // over NB*NJV = 65536
    float s = s_in[idx] + bias[idx & (NJV - 1)];
    float sq = s * s;
#pragma unroll
    for (int m = 1; m < 16; m <<= 1) sq += __shfl_xor(sq, m, 64);
    float val = s * sq / (1.0f + sq) / sqrtf(sq + 1e-9f);
    if (mode == 0)      Vacc[idx] = val;
    else if (mode == 1) Vacc[idx] += val;
    else                out[idx]  = val;
}

// ================= R5 fallback (proven) =================
#define FBI 16
#define FIC (NI / FBI)

template<int CTRL>
__device__ __forceinline__ float dpp_add(float x) {
    int t = __builtin_amdgcn_update_dpp(0, __float_as_int(x), CTRL, 0xf, 0xf, true);
    return x + __int_as_float(t);
}
__device__ __forceinline__ float red16(float x) {
    x = dpp_add<0xB1>(x); x = dpp_add<0x4E>(x);
    x = dpp_add<0x141>(x); x = dpp_add<0x140>(x);
    return x;
}

template<int MODE>
__global__ __launch_bounds__(256, 1)
void pass_fb(const float* __restrict__ x, const float* __restrict__ W,
             const float* __restrict__ Vacc, float* __restrict__ s_out)
{
    __shared__ float Wlds[2][8192];
    const int tid = threadIdx.x, lane = tid & 63, wave = tid >> 6;
    const int ibase = blockIdx.x * FBI;
    const int b0 = blockIdx.y * 32 + wave * 8;
    const int soff = ((tid >> 4) & 3) * 1024 + (tid & 15) * 64 + (tid >> 6) * 16;
    const char* Wbp = (const char*)W;
#define FSTAGE(i_, buf_) { const char* srcp = Wbp + (size_t)(i_) * 32768 + soff; \
    _Pragma("unroll") for (int p = 0; p < 8; ++p) \
        GLD16(srcp + p * 4096, &Wlds[buf_][p * 1024 + tid * 4]); }
    float vacc[8][8];
    if (MODE) {
#pragma unroll
        for (int b = 0; b < 8; ++b)
#pragma unroll
            for (int k = 0; k < 8; ++k)
                vacc[b][k] = Vacc[(size_t)(b0 + b) * NJV + lane + 64 * k];
    }
    float s_local[8][8];
#pragma unroll
    for (int b = 0; b < 8; ++b)
#pragma unroll
        for (int k = 0; k < 8; ++k) s_local[b][k] = 0.f;
    float uv[8][8];
    FSTAGE(ibase, 0);
    for (int il = 0; il < FBI; ++il) {
        const int i = ibase + il, cur = il & 1;
        if (il < FBI - 1) {
            FSTAGE(i + 1, cur ^ 1);
            asm volatile("s_waitcnt vmcnt(8)" ::: "memory");
        } else {
            asm volatile("s_waitcnt vmcnt(0)" ::: "memory");
        }
        __builtin_amdgcn_s_barrier();
        asm volatile("" ::: "memory");
#pragma unroll
        for (int q = 0; q < 4; ++q) {
            float4 xv[8];
#pragma unroll
            for (int b = 0; b < 8; ++b)
                xv[b] = *(const float4*)(x + ((size_t)(b0 + b) * NI + i) * NU + q * 4);
#pragma unroll
            for (int k = 0; k < 8; ++k) {
                float4 w = *(const float4*)&Wlds[cur][(k * 4 + q) * 256 + lane * 4];
#pragma unroll
                for (int b = 0; b < 8; ++b) {
                    if (MODE) {
                        float a = (q == 0) ? xv[b].x * w.x : fmaf(xv[b].x, w.x, uv[b][k]);
                        a = fmaf(xv[b].y, w.y, a); a = fmaf(xv[b].z, w.z, a);
                        a = fmaf(xv[b].w, w.w, a); uv[b][k] = a;
                    } else {
                        float a = fmaf(xv[b].x, w.x, s_local[b][k]);
                        a = fmaf(xv[b].y, w.y, a); a = fmaf(xv[b].z, w.z, a);
                        a = fmaf(xv[b].w, w.w, a); s_local[b][k] = a;
                    }
                }
            }
        }
        if (MODE) {
#pragma unroll
            for (int b = 0; b < 8; ++b) {
                float p8[8];
#pragma unroll
                for (int k = 0; k < 8; ++k) p8[k] = uv[b][k] * vacc[b][k];
#pragma unroll
                for (int k = 0; k < 8; ++k) p8[k] = red16(p8[k]);
                float sl = 0.f;
#pragma unroll
                for (int k = 0; k < 8; ++k) { p8[k] = __expf(p8[k]); sl += p8[k]; }
                sl += __int_as_float(__builtin_amdgcn_ds_swizzle(__float_as_int(sl), 0x401F));
                sl += __int_as_float(__builtin_amdgcn_ds_bpermute((lane ^ 32) << 2,
                                                                  __float_as_int(sl)));
                float inv = __builtin_amdgcn_rcpf(sl);
#pragma unroll
                for (int k = 0; k < 8; ++k)
                    s_local[b][k] = fmaf(p8[k] * inv, uv[b][k], s_local[b][k]);
            }
        }
        asm volatile("" ::: "memory");
        __builtin_amdgcn_s_barrier();
        asm volatile("" ::: "memory");
    }
    const float scale = (MODE == 0) ? (1.0f / NJ) : 1.0f;
#pragma unroll
    for (int b = 0; b < 8; ++b)
#pragma unroll
        for (int k = 0; k < 8; ++k)
            atomicAdd(&s_out[(size_t)(b0 + b) * NJV + lane + 64 * k],
                      s_local[b][k] * scale);
#undef FSTAGE
}

// ================= launch =================
extern "C" void kernel_launch(void* const* d_in, const int* in_sizes, int n_in,
                              void* d_out, int out_size, void* d_ws, size_t ws_size,
                              hipStream_t stream)
{
    const float* x    = (const float*)d_in[0];
    const float* W    = (const float*)d_in[1];
    const float* bias = (const float*)d_in[2];
    float* out = (float*)d_out;

    float* s_buf = (float*)d_ws;             // 256 KB (fallback only)
    float* Vacc  = s_buf + NB * NJV;         // 256 KB
    char*  Wb16  = (char*)(Vacc + NB * NJV); // 32 MB
    char*  xb16  = Wb16 + (size_t)33554432;  // 8 MB
    float* part  = (float*)(xb16 + (size_t)8388608);  // 32 MB

    const size_t NEED = 2u * NB * NJV * 4 + 33554432u + 8388608u + 33554432u;

    dim3 sgrid(NB * NJV / 256), sblk(256);
    size_t s_bytes = (size_t)NB * NJV * sizeof(float);

    if (ws_size >= NEED) {
        convert_W_kernel<<<8192, 256, 0, stream>>>(W, (uint4*)Wb16);
        convert_x_kernel<<<2048, 256, 0, stream>>>(x, (uint4*)xb16);

        dim3 grid(IC, 8), blk(256);
        dim3 rgrid(256), rblk(256);

        pass_mfma<0><<<grid, blk, 0, stream>>>(Wb16, xb16, Vacc, part);
        reduce_squash<<<rgrid, rblk, 0, stream>>>(part, bias, Vacc, out, 0);

        pass_mfma<1><<<grid, blk, 0, stream>>>(Wb16, xb16, Vacc, part);
        reduce_squash<<<rgrid, rblk, 0, stream>>>(part, bias, Vacc, out, 1);

        pass_mfma<1><<<grid, blk, 0, stream>>>(Wb16, xb16, Vacc, part);
        reduce_squash<<<rgrid, rblk, 0, stream>>>(part, bias, Vacc, out, 2);
    } else {
        dim3 grid(FIC, 4), blk(256);

        (void)hipMemsetAsync(s_buf, 0, s_bytes, stream);
        pass_fb<0><<<grid, blk, 0, stream>>>(x, W, Vacc, s_buf);
        squash_kernel<<<sgrid, sblk, 0, stream>>>(s_buf, bias, Vacc, out, 0);

        (void)hipMemsetAsync(s_buf, 0, s_bytes, stream);
        pass_fb<1><<<grid, blk, 0, stream>>>(x, W, Vacc, s_buf);
        squash_kernel<<<sgrid, sblk, 0, stream>>>(s_buf, bias, Vacc, out, 1);

        (void)hipMemsetAsync(s_buf, 0, s_bytes, stream);
        pass_fb<1><<<grid, blk, 0, stream>>>(x, W, Vacc, s_buf);
        squash_kernel<<<sgrid, sblk, 0, stream>>>(s_buf, bias, Vacc, out, 2);
    }
}